// Round 1
// baseline (467.181 us; speedup 1.0000x reference)
//
#include <hip/hip_runtime.h>

using u16 = unsigned short;
typedef __attribute__((ext_vector_type(8))) short short8;
typedef __attribute__((ext_vector_type(4))) float f32x4;

__device__ __forceinline__ u16 f2bf(float f) {
  unsigned int u = __float_as_uint(f);
  u = (u + 0x7FFFu + ((u >> 16) & 1u)) >> 16;   // RNE, fine for non-NaN
  return (u16)u;
}
__device__ __forceinline__ float bf2f(u16 v) {
  return __uint_as_float(((unsigned int)v) << 16);
}

#define B_ 4
#define S_ 4096
#define D_ 1024
#define H_ 16
#define HD_ 64
#define M_ (B_*S_)    // 16384
#define N1_ (3*D_)    // 3072

// workspace layout (bytes)
#define OFF_XB    0ull
#define OFF_WQKVT (OFF_XB    + (size_t)M_*D_*2)        // x as bf16 bits
#define OFF_WOT   (OFF_WQKVT + (size_t)N1_*D_*2)       // Wqkv^T bf16 [3072][1024]
#define OFF_QKV   (OFF_WOT   + (size_t)D_*D_*2)        // Wo^T bf16 [1024][1024]
#define OFF_KV    (OFF_QKV   + (size_t)M_*N1_*2)       // qkv bf16 (Q,K already elu+1)
#define OFF_KSUM  (OFF_KV    + (size_t)64*64*64*4)     // KV fp32 [bh][64][64]
#define OFF_ATTN  (OFF_KSUM  + (size_t)64*64*4)        // Ksum fp32 [bh][64]
#define WS_NEEDED (OFF_ATTN  + (size_t)M_*D_*2)        // attn bf16 [M][1024]

// ---------------- elementwise fp32 -> bf16 ----------------
__global__ void conv_bf16_kernel(const float* __restrict__ in, u16* __restrict__ out, int n4) {
  int i = blockIdx.x * blockDim.x + threadIdx.x;
  if (i < n4) {
    float4 v = ((const float4*)in)[i];
    uint2 o;
    o.x = (unsigned)f2bf(v.x) | ((unsigned)f2bf(v.y) << 16);
    o.y = (unsigned)f2bf(v.z) | ((unsigned)f2bf(v.w) << 16);
    ((uint2*)out)[i] = o;
  }
}

// ---------------- transpose + convert: in fp32 [R][C] -> out bf16 [C][R] ----------------
__global__ void transpose_conv(const float* __restrict__ in, u16* __restrict__ out, int R, int C) {
  __shared__ float tile[32][33];
  int tx = threadIdx.x, ty = threadIdx.y;
  int c0 = blockIdx.x * 32, r0 = blockIdx.y * 32;
#pragma unroll
  for (int i = 0; i < 4; i++)
    tile[ty + i*8][tx] = in[(size_t)(r0 + ty + i*8) * C + c0 + tx];
  __syncthreads();
#pragma unroll
  for (int i = 0; i < 4; i++)
    out[(size_t)(c0 + ty + i*8) * R + r0 + tx] = f2bf(tile[tx][ty + i*8]);
}

// ---------------- main GEMM: C[M,N] = A[M,K](bf16) * Bt[N,K](bf16)^T ----------------
// Cb!=null: store bf16, applying elu(x)+1 to cols < eluCols.  Cb==null: store fp32 to Cf.
__global__ __launch_bounds__(256) void gemm_bf16(
    const u16* __restrict__ A, const u16* __restrict__ Bt,
    float* __restrict__ Cf, u16* __restrict__ Cb,
    int M, int N, int K, int eluCols)
{
  __shared__ u16 As[128 * 40];   // stride 40 elems = 80B: 16B-aligned rows, 2-way banks (free)
  __shared__ u16 Bs[128 * 40];
  int tid = threadIdx.x;
  int bm = blockIdx.y * 128;
  int bn = blockIdx.x * 128;
  int wave = tid >> 6, lane = tid & 63;
  int quad = lane >> 4, l16 = lane & 15;
  int wr = (wave >> 1) * 64, wc = (wave & 1) * 64;

  f32x4 acc[4][4];
#pragma unroll
  for (int i = 0; i < 4; i++)
#pragma unroll
    for (int j = 0; j < 4; j++) acc[i][j] = (f32x4)0.0f;

  int arow = tid >> 1;
  int acol = (tid & 1) * 16;
  const u16* Ap = A  + (size_t)(bm + arow) * K + acol;
  const u16* Bp = Bt + (size_t)(bn + arow) * K + acol;
  u16* AsW = &As[arow * 40 + acol];
  u16* BsW = &Bs[arow * 40 + acol];

  for (int k0 = 0; k0 < K; k0 += 32) {
    uint4 a0 = *(const uint4*)(Ap + k0);
    uint4 a1 = *(const uint4*)(Ap + k0 + 8);
    uint4 b0 = *(const uint4*)(Bp + k0);
    uint4 b1 = *(const uint4*)(Bp + k0 + 8);
    __syncthreads();
    *(uint4*)(AsW)     = a0;
    *(uint4*)(AsW + 8) = a1;
    *(uint4*)(BsW)     = b0;
    *(uint4*)(BsW + 8) = b1;
    __syncthreads();
    short8 af[4], bfr[4];
#pragma unroll
    for (int i = 0; i < 4; i++) {
      af[i]  = *(const short8*)(&As[(wr + i*16 + l16) * 40 + quad*8]);
      bfr[i] = *(const short8*)(&Bs[(wc + i*16 + l16) * 40 + quad*8]);
    }
#pragma unroll
    for (int i = 0; i < 4; i++)
#pragma unroll
      for (int j = 0; j < 4; j++)
        acc[i][j] = __builtin_amdgcn_mfma_f32_16x16x32_bf16(af[i], bfr[j], acc[i][j], 0, 0, 0);
  }

  // C/D layout: col = lane&15, row = quad*4 + reg  (verified m89/m91)
#pragma unroll
  for (int i = 0; i < 4; i++) {
    int row0 = bm + wr + i*16 + quad*4;
#pragma unroll
    for (int j = 0; j < 4; j++) {
      int col = bn + wc + j*16 + l16;
#pragma unroll
      for (int r = 0; r < 4; r++) {
        float v = acc[i][j][r];
        size_t idx = (size_t)(row0 + r) * N + col;
        if (Cb) {
          if (col < eluCols) v = (v > 0.0f) ? (v + 1.0f) : __expf(v);  // elu+1
          Cb[idx] = f2bf(v);
        } else {
          Cf[idx] = v;
        }
      }
    }
  }
}

// ---------------- KV[d][v] = sum_s K[s,d]*V[s,v]; Ksum[d] = sum_s K[s,d] ----------------
__global__ __launch_bounds__(256) void kv_kernel(const u16* __restrict__ qkv,
                                                 float* __restrict__ KV,
                                                 float* __restrict__ Ksum)
{
  __shared__ u16 Ks[16][64];
  __shared__ u16 Vs[16][64];
  int tid = threadIdx.x;
  int bh = blockIdx.x;
  int b = bh >> 4, h = bh & 15;
  int s0 = blockIdx.y * 256;
  const u16* base = qkv + (size_t)(b * S_ + s0) * N1_;
  int d0 = (tid >> 4) * 4, v0 = (tid & 15) * 4;
  int lr = tid >> 4, lc = tid & 15;

  float acc[4][4] = {};
  float ksacc = 0.0f;

  for (int st = 0; st < 256; st += 16) {
    __syncthreads();
    const u16* rp = base + (size_t)(st + lr) * N1_;
    if (lc < 8) {
      *(uint4*)(&Ks[lr][lc * 8])       = *(const uint4*)(rp + D_   + h*HD_ + lc*8);
    } else {
      *(uint4*)(&Vs[lr][(lc - 8) * 8]) = *(const uint4*)(rp + 2*D_ + h*HD_ + (lc-8)*8);
    }
    __syncthreads();
#pragma unroll
    for (int r2 = 0; r2 < 16; ++r2) {
      float kd[4], vv[4];
#pragma unroll
      for (int i = 0; i < 4; i++) kd[i] = bf2f(Ks[r2][d0 + i]);
#pragma unroll
      for (int j = 0; j < 4; j++) vv[j] = bf2f(Vs[r2][v0 + j]);
#pragma unroll
      for (int i = 0; i < 4; i++)
#pragma unroll
        for (int j = 0; j < 4; j++)
          acc[i][j] = fmaf(kd[i], vv[j], acc[i][j]);
    }
    if (tid < 64) {
#pragma unroll
      for (int r2 = 0; r2 < 16; ++r2) ksacc += bf2f(Ks[r2][tid]);
    }
  }
  float* kvp = KV + (size_t)bh * 64 * 64;
#pragma unroll
  for (int i = 0; i < 4; i++)
#pragma unroll
    for (int j = 0; j < 4; j++)
      atomicAdd(&kvp[(d0 + i) * 64 + (v0 + j)], acc[i][j]);
  if (tid < 64) atomicAdd(&Ksum[bh * 64 + tid], ksacc);
}

// ---------------- attn[s][h*64+v] = (Q[s,:]@KV) / (Q[s,:]@Ksum + eps), bf16 out ----------------
__global__ __launch_bounds__(256) void attn_kernel(const u16* __restrict__ qkv,
                                                   const float* __restrict__ KV,
                                                   const float* __restrict__ Ksum,
                                                   u16* __restrict__ attn)
{
  __shared__ u16 KVt[64 * 72];   // [v][d], stride 72 elems = 144B = 9*16B: aligned, 2-way banks
  __shared__ float KsumS[64];
  __shared__ float normS[128];
  int tid = threadIdx.x;
  int bh = blockIdx.y;
  int b = bh >> 4, h = bh & 15;
  int s0 = blockIdx.x * 128;
  const float* kvsrc = KV + (size_t)bh * 4096;
  for (int i = tid; i < 4096; i += 256) {
    int d = i >> 6, v = i & 63;
    KVt[v * 72 + d] = f2bf(kvsrc[i]);
  }
  if (tid < 64) KsumS[tid] = Ksum[bh * 64 + tid];
  __syncthreads();
  if (tid < 128) {
    const u16* qrow = qkv + (size_t)(b * S_ + s0 + tid) * N1_ + h * HD_;
    float nacc = 0.f;
#pragma unroll
    for (int d = 0; d < 64; ++d) nacc += bf2f(qrow[d]) * KsumS[d];
    normS[tid] = nacc + 1e-6f;
  }
  __syncthreads();
  int wave = tid >> 6, lane = tid & 63, quad = lane >> 4, l16 = lane & 15;
  f32x4 acc[2][4];
#pragma unroll
  for (int i = 0; i < 2; i++)
#pragma unroll
    for (int j = 0; j < 4; j++) acc[i][j] = (f32x4)0.0f;

#pragma unroll
  for (int ks = 0; ks < 2; ++ks) {
    short8 bfr[4];
#pragma unroll
    for (int j = 0; j < 4; j++)
      bfr[j] = *(const short8*)(&KVt[(j*16 + l16) * 72 + ks*32 + quad*8]);
#pragma unroll
    for (int i = 0; i < 2; i++) {
      int row = s0 + wave * 32 + i * 16 + l16;
      short8 afr = *(const short8*)(qkv + (size_t)(b * S_ + row) * N1_ + h*HD_ + ks*32 + quad*8);
#pragma unroll
      for (int j = 0; j < 4; j++)
        acc[i][j] = __builtin_amdgcn_mfma_f32_16x16x32_bf16(afr, bfr[j], acc[i][j], 0, 0, 0);
    }
  }
#pragma unroll
  for (int i = 0; i < 2; i++) {
    int rb = wave * 32 + i * 16 + quad * 4;
#pragma unroll
    for (int j = 0; j < 4; j++) {
      int col = h * HD_ + j * 16 + l16;
#pragma unroll
      for (int r = 0; r < 4; r++) {
        float o = acc[i][j][r] / normS[rb + r];
        attn[(size_t)(b * S_ + s0 + rb + r) * D_ + col] = f2bf(o);
      }
    }
  }
}

extern "C" void kernel_launch(void* const* d_in, const int* in_sizes, int n_in,
                              void* d_out, int out_size, void* d_ws, size_t ws_size,
                              hipStream_t stream) {
  const float* x    = (const float*)d_in[0];
  const float* Wqkv = (const float*)d_in[1];
  const float* Wo   = (const float*)d_in[2];
  float* out = (float*)d_out;
  char* ws = (char*)d_ws;
  if (ws_size < WS_NEEDED) return;  // visible failure, no corruption

  u16*   xb    = (u16*)  (ws + OFF_XB);
  u16*   wqkvt = (u16*)  (ws + OFF_WQKVT);
  u16*   wot   = (u16*)  (ws + OFF_WOT);
  u16*   qkvb  = (u16*)  (ws + OFF_QKV);
  float* kv    = (float*)(ws + OFF_KV);
  float* ksum  = (float*)(ws + OFF_KSUM);
  u16*   attnb = (u16*)  (ws + OFF_ATTN);

  // KV + Ksum are adjacent; zero both (ws is re-poisoned 0xAA before every launch)
  hipMemsetAsync(kv, 0, (size_t)(64*64*64 + 64*64) * 4, stream);

  conv_bf16_kernel<<<(M_*D_/4 + 255)/256, 256, 0, stream>>>(x, xb, M_*D_/4);
  transpose_conv<<<dim3(N1_/32, D_/32), dim3(32, 8), 0, stream>>>(Wqkv, wqkvt, D_, N1_);
  transpose_conv<<<dim3(D_/32,  D_/32), dim3(32, 8), 0, stream>>>(Wo,   wot,   D_, D_);
  // qkv = x @ Wqkv, elu+1 on Q,K columns, bf16 out
  gemm_bf16<<<dim3(N1_/128, M_/128), 256, 0, stream>>>(xb, wqkvt, nullptr, qkvb, M_, N1_, D_, 2048);
  kv_kernel<<<dim3(64, 16), 256, 0, stream>>>(qkvb, kv, ksum);
  attn_kernel<<<dim3(32, 64), 256, 0, stream>>>(qkvb, kv, ksum, attnb);
  // final = attn @ Wo, fp32 out
  gemm_bf16<<<dim3(D_/128, M_/128), 256, 0, stream>>>(attnb, wot, out, nullptr, M_, D_, D_, 0);
}

// Round 2
// 422.344 us; speedup vs baseline: 1.1062x; 1.1062x over previous
//
#include <hip/hip_runtime.h>

using u16 = unsigned short;
typedef __attribute__((ext_vector_type(8))) short short8;
typedef __attribute__((ext_vector_type(4))) float f32x4;

__device__ __forceinline__ u16 f2bf(float f) {
  unsigned int u = __float_as_uint(f);
  u = (u + 0x7FFFu + ((u >> 16) & 1u)) >> 16;   // RNE, fine for non-NaN
  return (u16)u;
}
__device__ __forceinline__ float bf2f(u16 v) {
  return __uint_as_float(((unsigned int)v) << 16);
}

// async global->LDS, 16B per lane. LDS dest is wave-uniform base + lane*16.
__device__ __forceinline__ void gload16(const void* g, void* l) {
  __builtin_amdgcn_global_load_lds((const __attribute__((address_space(1))) void*)g,
                                   (__attribute__((address_space(3))) void*)l, 16, 0, 0);
}

#define B_ 4
#define S_ 4096
#define D_ 1024
#define H_ 16
#define HD_ 64
#define M_ (B_*S_)    // 16384
#define N1_ (3*D_)    // 3072

// workspace layout (bytes)
#define OFF_XB    0ull                                  // x bf16 [M][1024]; later Kt bf16 [64][64][4096]
#define OFF_WQKVT (OFF_XB    + (size_t)M_*D_*2)
#define OFF_WOT   (OFF_WQKVT + (size_t)N1_*D_*2)        // Wqkv^T bf16 [3072][1024]
#define OFF_QKV   (OFF_WOT   + (size_t)D_*D_*2)         // Wo^T bf16 [1024][1024]
#define OFF_KV    (OFF_QKV   + (size_t)M_*N1_*2)        // qkv bf16 (Q,K already elu+1)
#define OFF_KSUM  (OFF_KV    + (size_t)64*64*64*4)      // KV fp32 [bh][64][64]
#define OFF_VT    (OFF_KSUM  + (size_t)64*64*4)         // Vt bf16 [64][64][4096]; later attn bf16 [M][1024]
#define WS_NEEDED (OFF_VT    + (size_t)M_*D_*2)

// ---------------- elementwise fp32 -> bf16 ----------------
__global__ void conv_bf16_kernel(const float* __restrict__ in, u16* __restrict__ out, int n4) {
  int i = blockIdx.x * blockDim.x + threadIdx.x;
  if (i < n4) {
    float4 v = ((const float4*)in)[i];
    uint2 o;
    o.x = (unsigned)f2bf(v.x) | ((unsigned)f2bf(v.y) << 16);
    o.y = (unsigned)f2bf(v.z) | ((unsigned)f2bf(v.w) << 16);
    ((uint2*)out)[i] = o;
  }
}

// ---------------- transpose + convert: in fp32 [R][C] -> out bf16 [C][R] ----------------
__global__ void transpose_conv(const float* __restrict__ in, u16* __restrict__ out, int R, int C) {
  __shared__ float tile[32][33];
  int tx = threadIdx.x, ty = threadIdx.y;
  int c0 = blockIdx.x * 32, r0 = blockIdx.y * 32;
#pragma unroll
  for (int i = 0; i < 4; i++)
    tile[ty + i*8][tx] = in[(size_t)(r0 + ty + i*8) * C + c0 + tx];
  __syncthreads();
#pragma unroll
  for (int i = 0; i < 4; i++)
    out[(size_t)(c0 + ty + i*8) * R + r0 + tx] = f2bf(tile[tx][ty + i*8]);
}

// ---------------- main GEMM (m97 structure): C[M,N] = A[M,K](bf16) * Bt[N,K](bf16)^T ----------------
// global_load_lds width-16 staging; XOR chunk swizzle absorbed into the global fetch address.
// LDS tile 128x32 bf16, row r's stored 16B-chunk p holds logical chunk p ^ ((r>>1)&3).
// Cb!=null: store bf16, elu(x)+1 on cols < eluCols.  Cb==null: store fp32 to Cf.
__global__ __launch_bounds__(256) void gemm_bf16(
    const u16* __restrict__ A, const u16* __restrict__ Bt,
    float* __restrict__ Cf, u16* __restrict__ Cb,
    int M, int N, int K, int eluCols)
{
  __shared__ u16 As[128 * 32];
  __shared__ u16 Bs[128 * 32];
  int tid = threadIdx.x;
  int bm = blockIdx.y * 128;
  int bn = blockIdx.x * 128;
  int wave = tid >> 6, lane = tid & 63;
  int quad = lane >> 4, l16 = lane & 15;
  int wr = (wave >> 1) * 64, wc = (wave & 1) * 64;

  f32x4 acc[4][4];
#pragma unroll
  for (int i = 0; i < 4; i++)
#pragma unroll
    for (int j = 0; j < 4; j++) acc[i][j] = (f32x4)0.0f;

  // staging: lane covers row = wave*32 + t*16 + (lane>>2), stored chunk (lane&3);
  // logical chunk it must fetch = (lane&3) ^ ((lane>>3)&3)   (row>>1 mod 4 == (lane>>3)&3)
  int srow = wave * 32 + (lane >> 2);
  int c8 = ((lane & 3) ^ ((lane >> 3) & 3)) * 8;
  const u16* gA = A  + (size_t)(bm + srow) * K + c8;
  const u16* gB = Bt + (size_t)(bn + srow) * K + c8;
  size_t row16 = (size_t)16 * K;
  u16* lA = As + wave * 32 * 32;    // wave-uniform LDS bases
  u16* lB = Bs + wave * 32 * 32;

  // fragment read: row r, want logical chunk quad -> stored position quad ^ ((r>>1)&3);
  // wr,i*16 contribute 0 mod 4 after >>1, so position = quad ^ ((l16>>1)&3) for all i.
  int p8 = (quad ^ ((l16 >> 1) & 3)) * 8;

  for (int k0 = 0; k0 < K; k0 += 32) {
    __syncthreads();                       // prev tile fully consumed
    gload16(gA + k0,         lA);
    gload16(gA + k0 + row16, lA + 512);
    gload16(gB + k0,         lB);
    gload16(gB + k0 + row16, lB + 512);
    __syncthreads();                       // compiler drains vmcnt(0) before s_barrier
    short8 af[4], bfr[4];
#pragma unroll
    for (int i = 0; i < 4; i++) {
      af[i]  = *(const short8*)(&As[(wr + i*16 + l16) * 32 + p8]);
      bfr[i] = *(const short8*)(&Bs[(wc + i*16 + l16) * 32 + p8]);
    }
#pragma unroll
    for (int i = 0; i < 4; i++)
#pragma unroll
      for (int j = 0; j < 4; j++)
        acc[i][j] = __builtin_amdgcn_mfma_f32_16x16x32_bf16(af[i], bfr[j], acc[i][j], 0, 0, 0);
  }

  // C/D layout: col = lane&15, row = quad*4 + reg  (verified m89/m91)
#pragma unroll
  for (int i = 0; i < 4; i++) {
    int row0 = bm + wr + i*16 + quad*4;
#pragma unroll
    for (int j = 0; j < 4; j++) {
      int col = bn + wc + j*16 + l16;
#pragma unroll
      for (int r = 0; r < 4; r++) {
        float v = acc[i][j][r];
        size_t idx = (size_t)(row0 + r) * N + col;
        if (Cb) {
          if (col < eluCols) v = (v > 0.0f) ? (v + 1.0f) : __expf(v);  // elu+1
          Cb[idx] = f2bf(v);
        } else {
          Cf[idx] = v;
        }
      }
    }
  }
}

// ---------------- transpose K,V slices of qkv into Kt/Vt [bh][d][S] ----------------
__global__ __launch_bounds__(256) void kv_transpose(const u16* __restrict__ qkv,
                                                    u16* __restrict__ Kt,
                                                    u16* __restrict__ Vt)
{
  __shared__ u16 tK[64 * 72];   // [s][d], stride 72 elems (144B = 9*16B: aligned, slot-permuting)
  __shared__ u16 tV[64 * 72];
  int tid = threadIdx.x;
  int bh = blockIdx.y; int b = bh >> 4, h = bh & 15;
  int s0 = blockIdx.x * 64;
  int half = tid >> 7;          // waves 0,1: K   waves 2,3: V  (wave-uniform)
  int tt = tid & 127;
  const u16* src = qkv + (size_t)(b * S_ + s0) * N1_ + (half ? 2*D_ : D_) + h * HD_;
  u16* tile = half ? tV : tK;
  int sr = tt >> 3, chunk = tt & 7;
#pragma unroll
  for (int it = 0; it < 4; ++it)   // rows sr + it*16 -> covers all 64
    *(uint4*)(&tile[(sr + it*16) * 72 + chunk * 8]) =
        *(const uint4*)(src + (size_t)(sr + it*16) * N1_ + chunk * 8);
  __syncthreads();
  int l = tt & 63, w2 = tt >> 6;   // l = local s, w2 picks d-chunk group
  u16* dst = (half ? Vt : Kt) + (size_t)bh * 64 * 4096;
#pragma unroll
  for (int it = 0; it < 4; ++it) {
    int dchunk = w2 * 4 + it;
    short8 vrow = *(const short8*)(&tile[l * 72 + dchunk * 8]);   // 8 d's for one s
#pragma unroll
    for (int j = 0; j < 8; ++j)    // store: 64 lanes -> 128B contiguous per j
      dst[(size_t)(dchunk*8 + j) * 4096 + s0 + l] = ((const u16*)&vrow)[j];
  }
}

// ---------------- KV[d][v] = sum_s K[s,d]V[s,v] via MFMA on Kt/Vt; Ksum via ones-fragment ----------------
__global__ __launch_bounds__(256) void kv_kernel(const u16* __restrict__ Kt,
                                                 const u16* __restrict__ Vt,
                                                 float* __restrict__ KV,
                                                 float* __restrict__ Ksum)
{
  int tid = threadIdx.x;
  int bh = blockIdx.x;
  int ssplit = blockIdx.y;
  int wave = tid >> 6, lane = tid & 63, quad = lane >> 4, l16 = lane & 15;
  int sbase = ssplit * 1024 + wave * 256;
  const u16* Kb = Kt + (size_t)bh * 64 * 4096;
  const u16* Vb = Vt + (size_t)bh * 64 * 4096;
  short8 ones;
#pragma unroll
  for (int e = 0; e < 8; ++e) ones[e] = (short)0x3F80;   // bf16 1.0

  f32x4 acc[4][4], accs[4];
#pragma unroll
  for (int i = 0; i < 4; i++) {
    accs[i] = (f32x4)0.0f;
#pragma unroll
    for (int j = 0; j < 4; j++) acc[i][j] = (f32x4)0.0f;
  }

  for (int kk = 0; kk < 8; ++kk) {
    int s = sbase + kk * 32 + quad * 8;
    short8 af[4], bfr[4];
#pragma unroll
    for (int i = 0; i < 4; i++) {
      af[i]  = *(const short8*)(Kb + (size_t)(i*16 + l16) * 4096 + s);
      bfr[i] = *(const short8*)(Vb + (size_t)(i*16 + l16) * 4096 + s);
    }
#pragma unroll
    for (int i = 0; i < 4; i++) {
#pragma unroll
      for (int j = 0; j < 4; j++)
        acc[i][j] = __builtin_amdgcn_mfma_f32_16x16x32_bf16(af[i], bfr[j], acc[i][j], 0, 0, 0);
      accs[i] = __builtin_amdgcn_mfma_f32_16x16x32_bf16(af[i], ones, accs[i], 0, 0, 0);
    }
  }
  float* kvp = KV + (size_t)bh * 4096;
#pragma unroll
  for (int i = 0; i < 4; i++) {
    int d0 = i*16 + quad*4;
#pragma unroll
    for (int j = 0; j < 4; j++)
#pragma unroll
      for (int r = 0; r < 4; r++)
        atomicAdd(&kvp[(d0 + r) * 64 + j*16 + l16], acc[i][j][r]);
    if (l16 == 0)
#pragma unroll
      for (int r = 0; r < 4; r++)
        atomicAdd(&Ksum[bh * 64 + d0 + r], accs[i][r]);
  }
}

// ---------------- attn[s][h*64+v] = (Q[s,:]@KV) / (Q[s,:]@Ksum + eps), bf16 out ----------------
// Normalizer via Ksum loaded into ALL B-lanes: C[m][n] = sum_k Q[m,k]*Ksum[k] is n-independent,
// so each lane holds its own rows' normalizer in-register after the MFMA.
__global__ __launch_bounds__(256) void attn_kernel(const u16* __restrict__ qkv,
                                                   const float* __restrict__ KV,
                                                   const float* __restrict__ Ksum,
                                                   u16* __restrict__ attn)
{
  __shared__ u16 KVt[64 * 72];   // [v][d], stride 72
  int tid = threadIdx.x;
  int bh = blockIdx.y;
  int b = bh >> 4, h = bh & 15;
  int s0 = blockIdx.x * 128;
  const float* kvsrc = KV + (size_t)bh * 4096;
  for (int i = tid; i < 4096; i += 256) {
    int d = i >> 6, v = i & 63;
    KVt[v * 72 + d] = f2bf(kvsrc[i]);
  }
  __syncthreads();
  int wave = tid >> 6, lane = tid & 63, quad = lane >> 4, l16 = lane & 15;

  short8 bks[2];
#pragma unroll
  for (int ks = 0; ks < 2; ++ks)
#pragma unroll
    for (int jj = 0; jj < 8; ++jj)
      bks[ks][jj] = (short)f2bf(Ksum[bh * 64 + ks*32 + quad*8 + jj]);

  f32x4 acc[2][4], accn[2];
#pragma unroll
  for (int i = 0; i < 2; i++) {
    accn[i] = (f32x4)0.0f;
#pragma unroll
    for (int j = 0; j < 4; j++) acc[i][j] = (f32x4)0.0f;
  }

#pragma unroll
  for (int ks = 0; ks < 2; ++ks) {
    short8 bfr[4];
#pragma unroll
    for (int j = 0; j < 4; j++)
      bfr[j] = *(const short8*)(&KVt[(j*16 + l16) * 72 + ks*32 + quad*8]);
#pragma unroll
    for (int i = 0; i < 2; i++) {
      int row = s0 + wave * 32 + i * 16 + l16;
      short8 afr = *(const short8*)(qkv + (size_t)(b * S_ + row) * N1_ + h*HD_ + ks*32 + quad*8);
#pragma unroll
      for (int j = 0; j < 4; j++)
        acc[i][j] = __builtin_amdgcn_mfma_f32_16x16x32_bf16(afr, bfr[j], acc[i][j], 0, 0, 0);
      accn[i] = __builtin_amdgcn_mfma_f32_16x16x32_bf16(afr, bks[ks], accn[i], 0, 0, 0);
    }
  }
#pragma unroll
  for (int i = 0; i < 2; i++) {
    int rb = wave * 32 + i * 16 + quad * 4;
#pragma unroll
    for (int j = 0; j < 4; j++) {
      int col = h * HD_ + j * 16 + l16;
#pragma unroll
      for (int r = 0; r < 4; r++) {
        float o = acc[i][j][r] / (accn[i][r] + 1e-6f);
        attn[(size_t)(b * S_ + s0 + rb + r) * D_ + col] = f2bf(o);
      }
    }
  }
}

extern "C" void kernel_launch(void* const* d_in, const int* in_sizes, int n_in,
                              void* d_out, int out_size, void* d_ws, size_t ws_size,
                              hipStream_t stream) {
  const float* x    = (const float*)d_in[0];
  const float* Wqkv = (const float*)d_in[1];
  const float* Wo   = (const float*)d_in[2];
  float* out = (float*)d_out;
  char* ws = (char*)d_ws;
  if (ws_size < WS_NEEDED) return;  // visible failure, no corruption

  u16*   xb    = (u16*)  (ws + OFF_XB);
  u16*   kt    = (u16*)  (ws + OFF_XB);    // aliases xb: dead after gemm1
  u16*   wqkvt = (u16*)  (ws + OFF_WQKVT);
  u16*   wot   = (u16*)  (ws + OFF_WOT);
  u16*   qkvb  = (u16*)  (ws + OFF_QKV);
  float* kv    = (float*)(ws + OFF_KV);
  float* ksum  = (float*)(ws + OFF_KSUM);
  u16*   vt    = (u16*)  (ws + OFF_VT);
  u16*   attnb = (u16*)  (ws + OFF_VT);    // aliases Vt: dead after kv_kernel

  // KV + Ksum adjacent; zero both (ws re-poisoned 0xAA before every launch)
  hipMemsetAsync(kv, 0, (size_t)(64*64*64 + 64*64) * 4, stream);

  conv_bf16_kernel<<<(M_*D_/4 + 255)/256, 256, 0, stream>>>(x, xb, M_*D_/4);
  transpose_conv<<<dim3(N1_/32, D_/32), dim3(32, 8), 0, stream>>>(Wqkv, wqkvt, D_, N1_);
  transpose_conv<<<dim3(D_/32,  D_/32), dim3(32, 8), 0, stream>>>(Wo,   wot,   D_, D_);
  // qkv = x @ Wqkv, elu+1 on Q,K columns, bf16 out
  gemm_bf16<<<dim3(N1_/128, M_/128), 256, 0, stream>>>(xb, wqkvt, nullptr, qkvb, M_, N1_, D_, 2048);
  // K,V -> [bh][d][S] transposed layouts (Kt over xb, safe: stream-ordered after gemm1)
  kv_transpose<<<dim3(S_/64, 64), 256, 0, stream>>>(qkvb, kt, vt);
  kv_kernel<<<dim3(64, 4), 256, 0, stream>>>(kt, vt, kv, ksum);
  attn_kernel<<<dim3(32, 64), 256, 0, stream>>>(qkvb, kv, ksum, attnb);
  // final = attn @ Wo, fp32 out
  gemm_bf16<<<dim3(D_/128, M_/128), 256, 0, stream>>>(attnb, wot, out, nullptr, M_, D_, D_, 0);
}

// Round 3
// 421.755 us; speedup vs baseline: 1.1077x; 1.0014x over previous
//
#include <hip/hip_runtime.h>

using u16 = unsigned short;
typedef __attribute__((ext_vector_type(8))) short short8;
typedef __attribute__((ext_vector_type(4))) float f32x4;

__device__ __forceinline__ u16 f2bf(float f) {
  unsigned int u = __float_as_uint(f);
  u = (u + 0x7FFFu + ((u >> 16) & 1u)) >> 16;   // RNE, fine for non-NaN
  return (u16)u;
}
__device__ __forceinline__ float bf2f(u16 v) {
  return __uint_as_float(((unsigned int)v) << 16);
}

// async global->LDS, 16B per lane. LDS dest is wave-uniform base + lane*16.
__device__ __forceinline__ void gload16(const void* g, void* l) {
  __builtin_amdgcn_global_load_lds((const __attribute__((address_space(1))) void*)g,
                                   (__attribute__((address_space(3))) void*)l, 16, 0, 0);
}

#define B_ 4
#define S_ 4096
#define D_ 1024
#define H_ 16
#define HD_ 64
#define M_ (B_*S_)    // 16384
#define N1_ (3*D_)    // 3072

// workspace layout (bytes)
#define OFF_XB    0ull                                  // x bf16 [M][1024]
#define OFF_WQKVT (OFF_XB    + (size_t)M_*D_*2)         // Wqkv^T bf16 [3072][1024]
#define OFF_WOT   (OFF_WQKVT + (size_t)N1_*D_*2)        // Wo^T bf16 [1024][1024]
#define OFF_QBUF  (OFF_WOT   + (size_t)D_*D_*2)         // Q bf16 [M][1024] (elu+1 applied)
#define OFF_KT    (OFF_QBUF  + (size_t)M_*D_*2)         // Kt bf16 [64][64][4096] (elu+1); later attn bf16 [M][1024]
#define OFF_VT    (OFF_KT    + (size_t)M_*D_*2)         // Vt bf16 [64][64][4096]
#define OFF_KV    (OFF_VT    + (size_t)M_*D_*2)         // KV fp32 [bh][64][64]
#define OFF_KSUM  (OFF_KV    + (size_t)64*64*64*4)      // Ksum fp32 [bh][64]
#define WS_NEEDED (OFF_KSUM  + (size_t)64*64*4)

// ---------------- elementwise fp32 -> bf16 ----------------
__global__ void conv_bf16_kernel(const float* __restrict__ in, u16* __restrict__ out, int n4) {
  int i = blockIdx.x * blockDim.x + threadIdx.x;
  if (i < n4) {
    float4 v = ((const float4*)in)[i];
    uint2 o;
    o.x = (unsigned)f2bf(v.x) | ((unsigned)f2bf(v.y) << 16);
    o.y = (unsigned)f2bf(v.z) | ((unsigned)f2bf(v.w) << 16);
    ((uint2*)out)[i] = o;
  }
}

// ---------------- transpose + convert: in fp32 [R][C] -> out bf16 [C][R] ----------------
__global__ void transpose_conv(const float* __restrict__ in, u16* __restrict__ out, int R, int C) {
  __shared__ float tile[32][33];
  int tx = threadIdx.x, ty = threadIdx.y;
  int c0 = blockIdx.x * 32, r0 = blockIdx.y * 32;
#pragma unroll
  for (int i = 0; i < 4; i++)
    tile[ty + i*8][tx] = in[(size_t)(r0 + ty + i*8) * C + c0 + tx];
  __syncthreads();
#pragma unroll
  for (int i = 0; i < 4; i++)
    out[(size_t)(c0 + ty + i*8) * R + r0 + tx] = f2bf(tile[tx][ty + i*8]);
}

// ---------------- main GEMM (m97 structure): C[M,N] = A[M,K](bf16) * Bt[N,K](bf16)^T ----------------
// global_load_lds width-16 staging; XOR chunk swizzle absorbed into the global fetch address.
// mode 0: plain fp32 store to Cf.
// mode 1: qkv epilogue — bn<1024: Q (elu+1, bf16 -> qout[M][1024]);
//         1024<=bn<2048: K (elu+1, bf16, TRANSPOSED packed store -> Kt[bh][d][S]);
//         bn>=2048:      V (bf16, transposed packed -> Vt[bh][d][S]).
// C/D layout gives each lane 4 consecutive rows (s) for a fixed col (d) -> uint2 pack.
__global__ __launch_bounds__(256) void gemm_bf16(
    const u16* __restrict__ A, const u16* __restrict__ Bt,
    float* __restrict__ Cf, u16* __restrict__ qout,
    u16* __restrict__ Kt, u16* __restrict__ Vt,
    int M, int N, int K, int mode)
{
  __shared__ u16 As[128 * 32];
  __shared__ u16 Bs[128 * 32];
  int tid = threadIdx.x;
  int bm = blockIdx.y * 128;
  int bn = blockIdx.x * 128;
  int wave = tid >> 6, lane = tid & 63;
  int quad = lane >> 4, l16 = lane & 15;
  int wr = (wave >> 1) * 64, wc = (wave & 1) * 64;

  f32x4 acc[4][4];
#pragma unroll
  for (int i = 0; i < 4; i++)
#pragma unroll
    for (int j = 0; j < 4; j++) acc[i][j] = (f32x4)0.0f;

  // staging: lane covers row = wave*32 + (lane>>2), stored chunk (lane&3);
  // logical chunk to fetch = (lane&3) ^ ((row>>1)&3) = (lane&3) ^ ((lane>>3)&3)
  int srow = wave * 32 + (lane >> 2);
  int c8 = ((lane & 3) ^ ((lane >> 3) & 3)) * 8;
  const u16* gA = A  + (size_t)(bm + srow) * K + c8;
  const u16* gB = Bt + (size_t)(bn + srow) * K + c8;
  size_t row16 = (size_t)16 * K;
  u16* lA = As + wave * 32 * 32;    // wave-uniform LDS bases
  u16* lB = Bs + wave * 32 * 32;

  // fragment read: stored position of logical chunk quad = quad ^ ((l16>>1)&3)
  int p8 = (quad ^ ((l16 >> 1) & 3)) * 8;

  for (int k0 = 0; k0 < K; k0 += 32) {
    __syncthreads();                       // prev tile fully consumed
    gload16(gA + k0,         lA);
    gload16(gA + k0 + row16, lA + 512);
    gload16(gB + k0,         lB);
    gload16(gB + k0 + row16, lB + 512);
    __syncthreads();                       // vmcnt(0) drained before barrier
    short8 af[4], bfr[4];
#pragma unroll
    for (int i = 0; i < 4; i++) {
      af[i]  = *(const short8*)(&As[(wr + i*16 + l16) * 32 + p8]);
      bfr[i] = *(const short8*)(&Bs[(wc + i*16 + l16) * 32 + p8]);
    }
#pragma unroll
    for (int i = 0; i < 4; i++)
#pragma unroll
      for (int j = 0; j < 4; j++)
        acc[i][j] = __builtin_amdgcn_mfma_f32_16x16x32_bf16(af[i], bfr[j], acc[i][j], 0, 0, 0);
  }

  // C/D layout: col = lane&15 (+j*16), row = quad*4 + reg (verified m89/m91)
  if (mode == 0) {
#pragma unroll
    for (int i = 0; i < 4; i++) {
      int row0 = bm + wr + i*16 + quad*4;
#pragma unroll
      for (int j = 0; j < 4; j++) {
        int col = bn + wc + j*16 + l16;
#pragma unroll
        for (int r = 0; r < 4; r++)
          Cf[(size_t)(row0 + r) * N + col] = acc[i][j][r];
      }
    }
  } else {
    int cls = bn >> 10;   // 0=Q, 1=K, 2=V (block-uniform: 1024 % 128 == 0)
    if (cls == 0) {
#pragma unroll
      for (int i = 0; i < 4; i++) {
        int row0 = bm + wr + i*16 + quad*4;
#pragma unroll
        for (int j = 0; j < 4; j++) {
          int col = bn + wc + j*16 + l16;
#pragma unroll
          for (int r = 0; r < 4; r++) {
            float v = acc[i][j][r];
            v = (v > 0.0f) ? (v + 1.0f) : __expf(v);   // elu+1
            qout[(size_t)(row0 + r) * D_ + col] = f2bf(v);
          }
        }
      }
    } else {
      int b = bm >> 12;                      // 4096 rows per batch, bm % 4096 block-uniform
      int h = ((bn + wc) & 1023) >> 6;       // head of this wave's 64-col subtile
      u16* dst = (cls == 1 ? Kt : Vt) + (size_t)((b * 16 + h) * 64) * 4096;
      int sb = (bm & 4095) + wr;
      bool doElu = (cls == 1);
#pragma unroll
      for (int i = 0; i < 4; i++) {
        int s = sb + i*16 + quad*4;
#pragma unroll
        for (int j = 0; j < 4; j++) {
          int d = j*16 + l16;
          float v0 = acc[i][j][0], v1 = acc[i][j][1], v2 = acc[i][j][2], v3 = acc[i][j][3];
          if (doElu) {
            v0 = (v0 > 0.0f) ? (v0 + 1.0f) : __expf(v0);
            v1 = (v1 > 0.0f) ? (v1 + 1.0f) : __expf(v1);
            v2 = (v2 > 0.0f) ? (v2 + 1.0f) : __expf(v2);
            v3 = (v3 > 0.0f) ? (v3 + 1.0f) : __expf(v3);
          }
          uint2 o;
          o.x = (unsigned)f2bf(v0) | ((unsigned)f2bf(v1) << 16);
          o.y = (unsigned)f2bf(v2) | ((unsigned)f2bf(v3) << 16);
          *(uint2*)(dst + (size_t)d * 4096 + s) = o;   // 4 consecutive s, one d
        }
      }
    }
  }
}

// ---------------- KV[d][v] = sum_s K[s,d]V[s,v] via MFMA on Kt/Vt; Ksum via ones-fragment ----------------
__global__ __launch_bounds__(256) void kv_kernel(const u16* __restrict__ Kt,
                                                 const u16* __restrict__ Vt,
                                                 float* __restrict__ KV,
                                                 float* __restrict__ Ksum)
{
  int tid = threadIdx.x;
  int bh = blockIdx.x;
  int ssplit = blockIdx.y;
  int wave = tid >> 6, lane = tid & 63, quad = lane >> 4, l16 = lane & 15;
  int sbase = ssplit * 512 + wave * 128;
  const u16* Kb = Kt + (size_t)bh * 64 * 4096;
  const u16* Vb = Vt + (size_t)bh * 64 * 4096;
  short8 ones;
#pragma unroll
  for (int e = 0; e < 8; ++e) ones[e] = (short)0x3F80;   // bf16 1.0

  f32x4 acc[4][4], accs[4];
#pragma unroll
  for (int i = 0; i < 4; i++) {
    accs[i] = (f32x4)0.0f;
#pragma unroll
    for (int j = 0; j < 4; j++) acc[i][j] = (f32x4)0.0f;
  }

  for (int kk = 0; kk < 4; ++kk) {
    int s = sbase + kk * 32 + quad * 8;
    short8 af[4], bfr[4];
#pragma unroll
    for (int i = 0; i < 4; i++) {
      af[i]  = *(const short8*)(Kb + (size_t)(i*16 + l16) * 4096 + s);
      bfr[i] = *(const short8*)(Vb + (size_t)(i*16 + l16) * 4096 + s);
    }
#pragma unroll
    for (int i = 0; i < 4; i++) {
#pragma unroll
      for (int j = 0; j < 4; j++)
        acc[i][j] = __builtin_amdgcn_mfma_f32_16x16x32_bf16(af[i], bfr[j], acc[i][j], 0, 0, 0);
      accs[i] = __builtin_amdgcn_mfma_f32_16x16x32_bf16(af[i], ones, accs[i], 0, 0, 0);
    }
  }
  float* kvp = KV + (size_t)bh * 4096;
#pragma unroll
  for (int i = 0; i < 4; i++) {
    int d0 = i*16 + quad*4;
#pragma unroll
    for (int j = 0; j < 4; j++)
#pragma unroll
      for (int r = 0; r < 4; r++)
        atomicAdd(&kvp[(d0 + r) * 64 + j*16 + l16], acc[i][j][r]);
    if (l16 == 0)
#pragma unroll
      for (int r = 0; r < 4; r++)
        atomicAdd(&Ksum[bh * 64 + d0 + r], accs[i][r]);
  }
}

// ---------------- attn[s][h*64+v] = (Q[s,:]@KV) / (Q[s,:]@Ksum + eps), bf16 out ----------------
// Normalizer via Ksum broadcast into all B-lanes: C[m][n] = sum_k Q[m,k]*Ksum[k] is
// n-independent, so each lane gets its rows' normalizer in-register from one extra MFMA.
__global__ __launch_bounds__(256) void attn_kernel(const u16* __restrict__ qbuf,
                                                   const float* __restrict__ KV,
                                                   const float* __restrict__ Ksum,
                                                   u16* __restrict__ attn)
{
  __shared__ u16 KVt[64 * 72];   // [v][d], stride 72
  int tid = threadIdx.x;
  int bh = blockIdx.y;
  int b = bh >> 4, h = bh & 15;
  int s0 = blockIdx.x * 128;
  const float* kvsrc = KV + (size_t)bh * 4096;
  for (int i = tid; i < 4096; i += 256) {
    int d = i >> 6, v = i & 63;
    KVt[v * 72 + d] = f2bf(kvsrc[i]);
  }
  __syncthreads();
  int wave = tid >> 6, lane = tid & 63, quad = lane >> 4, l16 = lane & 15;

  short8 bks[2];
#pragma unroll
  for (int ks = 0; ks < 2; ++ks)
#pragma unroll
    for (int jj = 0; jj < 8; ++jj)
      bks[ks][jj] = (short)f2bf(Ksum[bh * 64 + ks*32 + quad*8 + jj]);

  f32x4 acc[2][4], accn[2];
#pragma unroll
  for (int i = 0; i < 2; i++) {
    accn[i] = (f32x4)0.0f;
#pragma unroll
    for (int j = 0; j < 4; j++) acc[i][j] = (f32x4)0.0f;
  }

#pragma unroll
  for (int ks = 0; ks < 2; ++ks) {
    short8 bfr[4];
#pragma unroll
    for (int j = 0; j < 4; j++)
      bfr[j] = *(const short8*)(&KVt[(j*16 + l16) * 72 + ks*32 + quad*8]);
#pragma unroll
    for (int i = 0; i < 2; i++) {
      int row = s0 + wave * 32 + i * 16 + l16;
      short8 afr = *(const short8*)(qbuf + (size_t)(b * S_ + row) * D_ + h*HD_ + ks*32 + quad*8);
#pragma unroll
      for (int j = 0; j < 4; j++)
        acc[i][j] = __builtin_amdgcn_mfma_f32_16x16x32_bf16(afr, bfr[j], acc[i][j], 0, 0, 0);
      accn[i] = __builtin_amdgcn_mfma_f32_16x16x32_bf16(afr, bks[ks], accn[i], 0, 0, 0);
    }
  }
#pragma unroll
  for (int i = 0; i < 2; i++) {
    int rb = wave * 32 + i * 16 + quad * 4;
#pragma unroll
    for (int j = 0; j < 4; j++) {
      int col = h * HD_ + j * 16 + l16;
#pragma unroll
      for (int r = 0; r < 4; r++) {
        float o = acc[i][j][r] / (accn[i][r] + 1e-6f);
        attn[(size_t)(b * S_ + s0 + rb + r) * D_ + col] = f2bf(o);
      }
    }
  }
}

extern "C" void kernel_launch(void* const* d_in, const int* in_sizes, int n_in,
                              void* d_out, int out_size, void* d_ws, size_t ws_size,
                              hipStream_t stream) {
  const float* x    = (const float*)d_in[0];
  const float* Wqkv = (const float*)d_in[1];
  const float* Wo   = (const float*)d_in[2];
  float* out = (float*)d_out;
  char* ws = (char*)d_ws;
  if (ws_size < WS_NEEDED) return;  // visible failure, no corruption

  u16*   xb    = (u16*)  (ws + OFF_XB);
  u16*   wqkvt = (u16*)  (ws + OFF_WQKVT);
  u16*   wot   = (u16*)  (ws + OFF_WOT);
  u16*   qbuf  = (u16*)  (ws + OFF_QBUF);
  u16*   kt    = (u16*)  (ws + OFF_KT);
  u16*   vt    = (u16*)  (ws + OFF_VT);
  float* kv    = (float*)(ws + OFF_KV);
  float* ksum  = (float*)(ws + OFF_KSUM);
  u16*   attnb = (u16*)  (ws + OFF_KT);    // aliases Kt: dead after kv_kernel

  // KV + Ksum adjacent; zero both (ws re-poisoned 0xAA before every launch)
  hipMemsetAsync(kv, 0, (size_t)(64*64*64 + 64*64) * 4, stream);

  conv_bf16_kernel<<<(M_*D_/4 + 255)/256, 256, 0, stream>>>(x, xb, M_*D_/4);
  transpose_conv<<<dim3(N1_/32, D_/32), dim3(32, 8), 0, stream>>>(Wqkv, wqkvt, D_, N1_);
  transpose_conv<<<dim3(D_/32,  D_/32), dim3(32, 8), 0, stream>>>(Wo,   wot,   D_, D_);
  // qkv = x @ Wqkv; epilogue splits Q (elu, [M][1024]) / Kt,Vt (transposed [bh][d][S])
  gemm_bf16<<<dim3(N1_/128, M_/128), 256, 0, stream>>>(xb, wqkvt, nullptr, qbuf, kt, vt,
                                                       M_, N1_, D_, 1);
  kv_kernel<<<dim3(64, 8), 256, 0, stream>>>(kt, vt, kv, ksum);
  attn_kernel<<<dim3(32, 64), 256, 0, stream>>>(qbuf, kv, ksum, attnb);
  // final = attn @ Wo, fp32 out
  gemm_bf16<<<dim3(D_/128, M_/128), 256, 0, stream>>>(attnb, wot, out, nullptr, nullptr, nullptr,
                                                      M_, D_, D_, 0);
}

// Round 4
// 397.766 us; speedup vs baseline: 1.1745x; 1.0603x over previous
//
#include <hip/hip_runtime.h>

using u16 = unsigned short;
typedef __attribute__((ext_vector_type(8))) short short8;
typedef __attribute__((ext_vector_type(4))) float f32x4;

__device__ __forceinline__ u16 f2bf(float f) {
  unsigned int u = __float_as_uint(f);
  u = (u + 0x7FFFu + ((u >> 16) & 1u)) >> 16;   // RNE, fine for non-NaN
  return (u16)u;
}
__device__ __forceinline__ float bf2f(u16 v) {
  return __uint_as_float(((unsigned int)v) << 16);
}

// async global->LDS, 16B per lane. LDS dest is wave-uniform base + lane*16.
__device__ __forceinline__ void gload16(const void* g, void* l) {
  __builtin_amdgcn_global_load_lds((const __attribute__((address_space(1))) void*)g,
                                   (__attribute__((address_space(3))) void*)l, 16, 0, 0);
}

#define B_ 4
#define S_ 4096
#define D_ 1024
#define H_ 16
#define HD_ 64
#define M_ (B_*S_)    // 16384
#define N1_ (3*D_)    // 3072
#define NSPLIT_ 4     // kv s-splits (partial buffers, no atomics)

// workspace layout (bytes)
#define OFF_XB    0ull                                  // x bf16 [M][1024]
#define OFF_WQKVT (OFF_XB    + (size_t)M_*D_*2)         // Wqkv^T bf16 [3072][1024]
#define OFF_WOT   (OFF_WQKVT + (size_t)N1_*D_*2)        // Wo^T bf16 [1024][1024]
#define OFF_QBUF  (OFF_WOT   + (size_t)D_*D_*2)         // Q bf16 [M][1024] (elu+1 applied)
#define OFF_KT    (OFF_QBUF  + (size_t)M_*D_*2)         // Kt bf16 [64][64][4096] (elu+1); later attn bf16 [M][1024]
#define OFF_VT    (OFF_KT    + (size_t)M_*D_*2)         // Vt bf16 [64][64][4096]
#define OFF_KV    (OFF_VT    + (size_t)M_*D_*2)         // KV partials fp32 [NSPLIT][bh][64*64]
#define OFF_KSUM  (OFF_KV    + (size_t)NSPLIT_*64*4096*4) // Ksum partials fp32 [NSPLIT][bh][64]
#define WS_NEEDED (OFF_KSUM  + (size_t)NSPLIT_*64*64*4)

// ---------------- merged prep: x->bf16, Wqkv^T, Wo^T (block-range switch) ----------------
// blocks [0,16384): conv x (float4/thread); [16384,19456): Wqkv transpose; [19456,20480): Wo.
__global__ __launch_bounds__(256) void prep_kernel(const float* __restrict__ x, u16* __restrict__ xb,
                                                   const float* __restrict__ Wqkv, u16* __restrict__ wqkvt,
                                                   const float* __restrict__ Wo, u16* __restrict__ wot)
{
  __shared__ float tile[32][33];
  int bid = blockIdx.x, tid = threadIdx.x;
  if (bid < 16384) {
    int i = bid * 256 + tid;               // n4 = M_*D_/4 = 4194304 > 16384*256 exactly
    float4 v = ((const float4*)x)[i];
    uint2 o;
    o.x = (unsigned)f2bf(v.x) | ((unsigned)f2bf(v.y) << 16);
    o.y = (unsigned)f2bf(v.z) | ((unsigned)f2bf(v.w) << 16);
    ((uint2*)xb)[i] = o;
    return;
  }
  const float* in; u16* out; int R, C, cb, rb;
  if (bid < 19456) {
    int t = bid - 16384;  in = Wqkv; out = wqkvt; R = D_; C = N1_;
    cb = t % 96; rb = t / 96;              // grid was (96, 32)
  } else {
    int t = bid - 19456;  in = Wo; out = wot; R = D_; C = D_;
    cb = t % 32; rb = t / 32;              // grid was (32, 32)
  }
  int tx = tid & 31, ty = tid >> 5;
  int c0 = cb * 32, r0 = rb * 32;
#pragma unroll
  for (int i = 0; i < 4; i++)
    tile[ty + i*8][tx] = in[(size_t)(r0 + ty + i*8) * C + c0 + tx];
  __syncthreads();
#pragma unroll
  for (int i = 0; i < 4; i++)
    out[(size_t)(c0 + ty + i*8) * R + r0 + tx] = f2bf(tile[tx][ty + i*8]);
}

// ---------------- main GEMM (m97 structure): C[M,N] = A[M,K](bf16) * Bt[N,K](bf16)^T ----------------
// global_load_lds width-16 staging; XOR chunk swizzle absorbed into the global fetch address.
// mode 0: plain fp32 store to Cf.
// mode 1: qkv epilogue — bn<1024: Q (elu+1, bf16 -> qout[M][1024]);
//         1024<=bn<2048: K (elu+1, bf16, transposed packed -> Kt[bh][d][S]);
//         bn>=2048:      V (bf16, transposed packed -> Vt[bh][d][S]).
__global__ __launch_bounds__(256) void gemm_bf16(
    const u16* __restrict__ A, const u16* __restrict__ Bt,
    float* __restrict__ Cf, u16* __restrict__ qout,
    u16* __restrict__ Kt, u16* __restrict__ Vt,
    int M, int N, int K, int mode)
{
  __shared__ u16 As[128 * 32];
  __shared__ u16 Bs[128 * 32];
  int tid = threadIdx.x;
  int bm = blockIdx.y * 128;
  int bn = blockIdx.x * 128;
  int wave = tid >> 6, lane = tid & 63;
  int quad = lane >> 4, l16 = lane & 15;
  int wr = (wave >> 1) * 64, wc = (wave & 1) * 64;

  f32x4 acc[4][4];
#pragma unroll
  for (int i = 0; i < 4; i++)
#pragma unroll
    for (int j = 0; j < 4; j++) acc[i][j] = (f32x4)0.0f;

  // staging: lane covers row = wave*32 + (lane>>2), stored chunk (lane&3);
  // logical chunk to fetch = (lane&3) ^ ((row>>1)&3) = (lane&3) ^ ((lane>>3)&3)
  int srow = wave * 32 + (lane >> 2);
  int c8 = ((lane & 3) ^ ((lane >> 3) & 3)) * 8;
  const u16* gA = A  + (size_t)(bm + srow) * K + c8;
  const u16* gB = Bt + (size_t)(bn + srow) * K + c8;
  size_t row16 = (size_t)16 * K;
  u16* lA = As + wave * 32 * 32;    // wave-uniform LDS bases
  u16* lB = Bs + wave * 32 * 32;

  // fragment read: stored position of logical chunk quad = quad ^ ((l16>>1)&3)
  int p8 = (quad ^ ((l16 >> 1) & 3)) * 8;

  for (int k0 = 0; k0 < K; k0 += 32) {
    __syncthreads();                       // prev tile fully consumed
    gload16(gA + k0,         lA);
    gload16(gA + k0 + row16, lA + 512);
    gload16(gB + k0,         lB);
    gload16(gB + k0 + row16, lB + 512);
    __syncthreads();                       // vmcnt(0) drained before barrier
    short8 af[4], bfr[4];
#pragma unroll
    for (int i = 0; i < 4; i++) {
      af[i]  = *(const short8*)(&As[(wr + i*16 + l16) * 32 + p8]);
      bfr[i] = *(const short8*)(&Bs[(wc + i*16 + l16) * 32 + p8]);
    }
#pragma unroll
    for (int i = 0; i < 4; i++)
#pragma unroll
      for (int j = 0; j < 4; j++)
        acc[i][j] = __builtin_amdgcn_mfma_f32_16x16x32_bf16(af[i], bfr[j], acc[i][j], 0, 0, 0);
  }

  // C/D layout: col = lane&15 (+j*16), row = quad*4 + reg (verified m89/m91)
  if (mode == 0) {
#pragma unroll
    for (int i = 0; i < 4; i++) {
      int row0 = bm + wr + i*16 + quad*4;
#pragma unroll
      for (int j = 0; j < 4; j++) {
        int col = bn + wc + j*16 + l16;
#pragma unroll
        for (int r = 0; r < 4; r++)
          Cf[(size_t)(row0 + r) * N + col] = acc[i][j][r];
      }
    }
  } else {
    int cls = bn >> 10;   // 0=Q, 1=K, 2=V (block-uniform: 1024 % 128 == 0)
    if (cls == 0) {
#pragma unroll
      for (int i = 0; i < 4; i++) {
        int row0 = bm + wr + i*16 + quad*4;
#pragma unroll
        for (int j = 0; j < 4; j++) {
          int col = bn + wc + j*16 + l16;
#pragma unroll
          for (int r = 0; r < 4; r++) {
            float v = acc[i][j][r];
            v = (v > 0.0f) ? (v + 1.0f) : __expf(v);   // elu+1
            qout[(size_t)(row0 + r) * D_ + col] = f2bf(v);
          }
        }
      }
    } else {
      int b = bm >> 12;                      // 4096 rows per batch, bm % 4096 block-uniform
      int h = ((bn + wc) & 1023) >> 6;       // head of this wave's 64-col subtile
      u16* dst = (cls == 1 ? Kt : Vt) + (size_t)((b * 16 + h) * 64) * 4096;
      int sb = (bm & 4095) + wr;
      bool doElu = (cls == 1);
#pragma unroll
      for (int i = 0; i < 4; i++) {
        int s = sb + i*16 + quad*4;
#pragma unroll
        for (int j = 0; j < 4; j++) {
          int d = j*16 + l16;
          float v0 = acc[i][j][0], v1 = acc[i][j][1], v2 = acc[i][j][2], v3 = acc[i][j][3];
          if (doElu) {
            v0 = (v0 > 0.0f) ? (v0 + 1.0f) : __expf(v0);
            v1 = (v1 > 0.0f) ? (v1 + 1.0f) : __expf(v1);
            v2 = (v2 > 0.0f) ? (v2 + 1.0f) : __expf(v2);
            v3 = (v3 > 0.0f) ? (v3 + 1.0f) : __expf(v3);
          }
          uint2 o;
          o.x = (unsigned)f2bf(v0) | ((unsigned)f2bf(v1) << 16);
          o.y = (unsigned)f2bf(v2) | ((unsigned)f2bf(v3) << 16);
          *(uint2*)(dst + (size_t)d * 4096 + s) = o;   // 4 consecutive s, one d
        }
      }
    }
  }
}

// ---------------- KV partial[p][bh] = sum_{s in split p} K[s,d]V[s,v]; NO global atomics ----------------
// Each wave MFMAs a full 64x64 tile over its s-range; waves merge via LDS ds_add_f32;
// block plain-stores its 16KB partial. attn_kernel sums the NSPLIT_ partials (L2-resident).
__global__ __launch_bounds__(256) void kv_kernel(const u16* __restrict__ Kt,
                                                 const u16* __restrict__ Vt,
                                                 float* __restrict__ KVp,
                                                 float* __restrict__ Ksp)
{
  __shared__ float red[4096];
  __shared__ float redS[64];
  int tid = threadIdx.x;
  int bh = blockIdx.x;
  int ssplit = blockIdx.y;
  int wave = tid >> 6, lane = tid & 63, quad = lane >> 4, l16 = lane & 15;
  int sbase = ssplit * (S_ / NSPLIT_) + wave * (S_ / NSPLIT_ / 4);
  const u16* Kb = Kt + (size_t)bh * 64 * 4096;
  const u16* Vb = Vt + (size_t)bh * 64 * 4096;
  short8 ones;
#pragma unroll
  for (int e = 0; e < 8; ++e) ones[e] = (short)0x3F80;   // bf16 1.0

  for (int i = tid; i < 4096; i += 256) red[i] = 0.0f;
  if (tid < 64) redS[tid] = 0.0f;

  f32x4 acc[4][4], accs[4];
#pragma unroll
  for (int i = 0; i < 4; i++) {
    accs[i] = (f32x4)0.0f;
#pragma unroll
    for (int j = 0; j < 4; j++) acc[i][j] = (f32x4)0.0f;
  }

  for (int kk = 0; kk < S_ / NSPLIT_ / 4 / 32; ++kk) {   // 8 iters of 32 s
    int s = sbase + kk * 32 + quad * 8;
    short8 af[4], bfr[4];
#pragma unroll
    for (int i = 0; i < 4; i++) {
      af[i]  = *(const short8*)(Kb + (size_t)(i*16 + l16) * 4096 + s);
      bfr[i] = *(const short8*)(Vb + (size_t)(i*16 + l16) * 4096 + s);
    }
#pragma unroll
    for (int i = 0; i < 4; i++) {
#pragma unroll
      for (int j = 0; j < 4; j++)
        acc[i][j] = __builtin_amdgcn_mfma_f32_16x16x32_bf16(af[i], bfr[j], acc[i][j], 0, 0, 0);
      accs[i] = __builtin_amdgcn_mfma_f32_16x16x32_bf16(af[i], ones, accs[i], 0, 0, 0);
    }
  }
  __syncthreads();   // zeroing complete (all threads passed it before this barrier)
#pragma unroll
  for (int i = 0; i < 4; i++) {
    int d0 = i*16 + quad*4;
#pragma unroll
    for (int j = 0; j < 4; j++)
#pragma unroll
      for (int r = 0; r < 4; r++)
        atomicAdd(&red[(d0 + r) * 64 + j*16 + l16], acc[i][j][r]);   // LDS ds_add_f32
    if (l16 == 0)
#pragma unroll
      for (int r = 0; r < 4; r++)
        atomicAdd(&redS[d0 + r], accs[i][r]);
  }
  __syncthreads();
  float* dst = KVp + ((size_t)ssplit * 64 + bh) * 4096;
  for (int i = tid; i < 4096; i += 256) dst[i] = red[i];
  if (tid < 64) Ksp[((size_t)ssplit * 64 + bh) * 64 + tid] = redS[tid];
}

// ---------------- attn[s][h*64+v] = (Q[s,:]@KV) / (Q[s,:]@Ksum + eps), bf16 out ----------------
// Sums the NSPLIT_ KV/Ksum partials inline (L2-resident). Normalizer via Ksum broadcast
// into all B-lanes: one extra MFMA puts each row's normalizer in-register.
__global__ __launch_bounds__(256) void attn_kernel(const u16* __restrict__ qbuf,
                                                   const float* __restrict__ KVp,
                                                   const float* __restrict__ Ksp,
                                                   u16* __restrict__ attn)
{
  __shared__ u16 KVt[64 * 72];   // [v][d], stride 72
  int tid = threadIdx.x;
  int bh = blockIdx.y;
  int b = bh >> 4, h = bh & 15;
  int s0 = blockIdx.x * 128;
  const float* kvsrc = KVp + (size_t)bh * 4096;
  for (int i = tid; i < 4096; i += 256) {
    float s = kvsrc[i] + kvsrc[i + 64*4096] + kvsrc[i + 2*64*4096] + kvsrc[i + 3*64*4096];
    int d = i >> 6, v = i & 63;
    KVt[v * 72 + d] = f2bf(s);
  }
  __syncthreads();
  int wave = tid >> 6, lane = tid & 63, quad = lane >> 4, l16 = lane & 15;

  const float* kssrc = Ksp + (size_t)bh * 64;
  short8 bks[2];
#pragma unroll
  for (int ks = 0; ks < 2; ++ks)
#pragma unroll
    for (int jj = 0; jj < 8; ++jj) {
      int d = ks*32 + quad*8 + jj;
      float s = kssrc[d] + kssrc[d + 64*64] + kssrc[d + 2*64*64] + kssrc[d + 3*64*64];
      bks[ks][jj] = (short)f2bf(s);
    }

  f32x4 acc[2][4], accn[2];
#pragma unroll
  for (int i = 0; i < 2; i++) {
    accn[i] = (f32x4)0.0f;
#pragma unroll
    for (int j = 0; j < 4; j++) acc[i][j] = (f32x4)0.0f;
  }

#pragma unroll
  for (int ks = 0; ks < 2; ++ks) {
    short8 bfr[4];
#pragma unroll
    for (int j = 0; j < 4; j++)
      bfr[j] = *(const short8*)(&KVt[(j*16 + l16) * 72 + ks*32 + quad*8]);
#pragma unroll
    for (int i = 0; i < 2; i++) {
      int row = s0 + wave * 32 + i * 16 + l16;
      short8 afr = *(const short8*)(qbuf + (size_t)(b * S_ + row) * D_ + h*HD_ + ks*32 + quad*8);
#pragma unroll
      for (int j = 0; j < 4; j++)
        acc[i][j] = __builtin_amdgcn_mfma_f32_16x16x32_bf16(afr, bfr[j], acc[i][j], 0, 0, 0);
      accn[i] = __builtin_amdgcn_mfma_f32_16x16x32_bf16(afr, bks[ks], accn[i], 0, 0, 0);
    }
  }
#pragma unroll
  for (int i = 0; i < 2; i++) {
    int rb = wave * 32 + i * 16 + quad * 4;
#pragma unroll
    for (int j = 0; j < 4; j++) {
      int col = h * HD_ + j * 16 + l16;
#pragma unroll
      for (int r = 0; r < 4; r++) {
        float o = acc[i][j][r] / (accn[i][r] + 1e-6f);
        attn[(size_t)(b * S_ + s0 + rb + r) * D_ + col] = f2bf(o);
      }
    }
  }
}

extern "C" void kernel_launch(void* const* d_in, const int* in_sizes, int n_in,
                              void* d_out, int out_size, void* d_ws, size_t ws_size,
                              hipStream_t stream) {
  const float* x    = (const float*)d_in[0];
  const float* Wqkv = (const float*)d_in[1];
  const float* Wo   = (const float*)d_in[2];
  float* out = (float*)d_out;
  char* ws = (char*)d_ws;
  if (ws_size < WS_NEEDED) return;  // visible failure, no corruption

  u16*   xb    = (u16*)  (ws + OFF_XB);
  u16*   wqkvt = (u16*)  (ws + OFF_WQKVT);
  u16*   wot   = (u16*)  (ws + OFF_WOT);
  u16*   qbuf  = (u16*)  (ws + OFF_QBUF);
  u16*   kt    = (u16*)  (ws + OFF_KT);
  u16*   vt    = (u16*)  (ws + OFF_VT);
  float* kvp   = (float*)(ws + OFF_KV);
  float* ksp   = (float*)(ws + OFF_KSUM);
  u16*   attnb = (u16*)  (ws + OFF_KT);    // aliases Kt: dead after kv_kernel

  prep_kernel<<<20480, 256, 0, stream>>>(x, xb, Wqkv, wqkvt, Wo, wot);
  // qkv = x @ Wqkv; epilogue splits Q (elu, [M][1024]) / Kt,Vt (transposed [bh][d][S])
  gemm_bf16<<<dim3(N1_/128, M_/128), 256, 0, stream>>>(xb, wqkvt, nullptr, qbuf, kt, vt,
                                                       M_, N1_, D_, 1);
  kv_kernel<<<dim3(64, NSPLIT_), 256, 0, stream>>>(kt, vt, kvp, ksp);
  attn_kernel<<<dim3(32, 64), 256, 0, stream>>>(qbuf, kvp, ksp, attnb);
  // final = attn @ Wo, fp32 out
  gemm_bf16<<<dim3(D_/128, M_/128), 256, 0, stream>>>(attnb, wot, out, nullptr, nullptr, nullptr,
                                                      M_, D_, D_, 0);
}